// Round 16
// baseline (31.319 us; speedup 1.0000x reference)
//
#include <hip/hip_runtime.h>
#include <math.h>

#define RES 96
#define NV 97
#define NV2 (NV * NV)                      // 9409
#define NVERT (NV * NV * NV)               // 912673
#define NCELLS (RES * RES * RES)           // 884736
#define NBLK 3456
#define MAX_DISP (2.0f / 96.0f / 4.0f)

typedef float f32x2u __attribute__((ext_vector_type(2), aligned(4)));

__device__ __forceinline__ float grid_coord(int a) {
    // linspace(-0.5,0.5,97)[a] * 2  ==  a/48 - 1
    return fmaf((float)a, 1.0f / 48.0f, -1.0f);
}

__device__ __forceinline__ float fast_tanh(float x) {
    x = fminf(fmaxf(x, -15.f), 15.f);
    const float e = __expf(2.f * x);
    return (e - 1.f) * __builtin_amdgcn_rcpf(e + 1.f);
}

// Pass 1: one thread per vertex -> packed (x,y,z,sdf) float4 in d_ws.
// Tanh computed exactly once per vertex (vs x1.66 halo redundancy in the
// tiled-staging variant) and pass 2 needs no LDS/barrier at all.
__global__ __launch_bounds__(256) void flexi_vdef(
    const float* __restrict__ sdf,
    const float* __restrict__ deform,
    float4* __restrict__ vdef4)
{
    const int v = blockIdx.x * 256 + threadIdx.x;
    if (v >= NVERT) return;
    const int a = v / NV2;
    const int r = v - a * NV2;
    const int b = r / NV;
    const int cc = r - b * NV;
    const float* dp = deform + (size_t)v * 3;
    const f32x2u d01 = *reinterpret_cast<const f32x2u*>(dp);
    const float  d2  = dp[2];
    float4 vv;
    vv.x = grid_coord(a)  + MAX_DISP * fast_tanh(d01.x);
    vv.y = grid_coord(b)  + MAX_DISP * fast_tanh(d01.y);
    vv.z = grid_coord(cc) + MAX_DISP * fast_tanh(d2);
    vv.w = sdf[v];
    vdef4[v] = vv;
}

// Pass 2: one thread per cell, NO LDS staging, NO block barrier (except the
// 2-op tail reduction). 8 corner gathers are single dwordx4 loads from the
// L2/L3-resident vdef array — lane-consecutive k => coalesced 16B/lane.
// Waves progress independently => latency-tolerant without lockstep stalls.
// Hard-won constraints: single-pass edge loop with p[] in regs (R14), no nt
// hints (R12), no same-address atomic tails (R6/R7), no forced VGPR bounds
// (R11).
__global__ __launch_bounds__(256) void flexi_main(
    const float4* __restrict__ vdef4,
    const float* __restrict__ weights,
    float* __restrict__ out_vd,
    float* __restrict__ partial)
{
    const int t = threadIdx.x;
    // chunked XCD swizzle (bijective: 3456 = 8*432): each XCD gets a
    // contiguous i-slab => its vdef working set (~2MB) stays L2-resident.
    const int bidx = (blockIdx.x & 7) * 432 + (blockIdx.x >> 3);
    const int c = bidx * 256 + t;

    const int ci = c / 9216;
    const int r0 = c - ci * 9216;
    const int cj = r0 / 96;
    const int ck = r0 - cj * 96;
    const int v0 = ci * NV2 + cj * NV + ck;

    // reference corner order (di,dj,dk): offsets di*9409 + dj*97 + dk
    const int OFF[8] = {0, 9409, 97, 9506, 1, 9410, 98, 9507};

    float s[8], x[8][3];
    #pragma unroll
    for (int k = 0; k < 8; ++k) {
        const float4 vv = vdef4[v0 + OFF[k]];
        x[k][0] = vv.x; x[k][1] = vv.y; x[k][2] = vv.z;
        s[k] = vv.w;
    }

    const float* wrow = weights + (size_t)c * 21;
    float myw[21];                         // beta[0..11], alpha[12..19], gamma[20]
    #pragma unroll
    for (int e = 0; e < 21; ++e) myw[e] = wrow[e];

    const int EA[12] = {0, 1, 4, 0, 2, 3, 6, 2, 2, 3, 7, 6};
    const int EB[12] = {1, 5, 5, 4, 3, 7, 7, 6, 0, 1, 5, 4};

    float p[12][3];
    bool  cross[12];
    float wsum = 0.f, vnum0 = 0.f, vnum1 = 0.f, vnum2 = 0.f;
    int   ncross = 0;
    #pragma unroll
    for (int e = 0; e < 12; ++e) {
        const int a = EA[e], b = EB[e];
        const float sa = s[a], sb = s[b];
        const bool cr = (sa > 0.f) != (sb > 0.f);
        cross[e] = cr;
        const float ta = myw[12 + a] * sb;
        const float tb = myw[12 + b] * sa;
        // den guard keeps p finite (w=0 masks its value, but 0*inf = NaN)
        const float den = cr ? (ta - tb) : 1.0f;
        const float inv = __builtin_amdgcn_rcpf(den);
        const float p0 = (ta * x[a][0] - tb * x[b][0]) * inv;
        const float p1 = (ta * x[a][1] - tb * x[b][1]) * inv;
        const float p2 = (ta * x[a][2] - tb * x[b][2]) * inv;
        p[e][0] = p0; p[e][1] = p1; p[e][2] = p2;
        const float w = cr ? myw[e] : 0.f;
        wsum  += w;
        vnum0 += w * p0;
        vnum1 += w * p1;
        vnum2 += w * p2;
        ncross += cr ? 1 : 0;
    }

    const bool surf = (ncross > 0);
    const float invden = __builtin_amdgcn_rcpf(surf ? wsum : 1.0f);
    float vd0 = vnum0 * invden;
    float vd1 = vnum1 * invden;
    float vd2 = vnum2 * invden;
    if (!surf) { vd0 = 0.f; vd1 = 0.f; vd2 = 0.f; }

    out_vd[(size_t)c * 3 + 0] = vd0;
    out_vd[(size_t)c * 3 + 1] = vd1;
    out_vd[(size_t)c * 3 + 2] = vd2;

    float devsum = 0.f;
    #pragma unroll
    for (int e = 0; e < 12; ++e) {
        const float d0 = p[e][0] - vd0;
        const float d1 = p[e][1] - vd1;
        const float d2 = p[e][2] - vd2;
        const float nrm = __builtin_amdgcn_sqrtf(d0 * d0 + d1 * d1 + d2 * d2 + 1e-12f);
        devsum += cross[e] ? nrm : 0.f;
    }
    const float dev = devsum * __builtin_amdgcn_rcpf(fmaxf((float)ncross, 1.0f));
    float regc = surf ? dev * myw[20] : 0.f;
    float cnt  = surf ? 1.0f : 0.f;

    #pragma unroll
    for (int off = 32; off > 0; off >>= 1) {
        regc += __shfl_down(regc, off);
        cnt  += __shfl_down(cnt, off);
    }
    __shared__ float sm[8];
    const int wid = t >> 6;
    if ((t & 63) == 0) { sm[wid] = regc; sm[4 + wid] = cnt; }
    __syncthreads();
    if (t == 0) {
        partial[bidx]        = sm[0] + sm[1] + sm[2] + sm[3];
        partial[NBLK + bidx] = sm[4] + sm[5] + sm[6] + sm[7];
    }
}

__global__ __launch_bounds__(1024) void flexi_reduce(
    const float* __restrict__ partial, float* __restrict__ reg_out)
{
    float a = 0.f, b = 0.f;
    for (int i = threadIdx.x; i < NBLK; i += 1024) {
        a += partial[i];
        b += partial[NBLK + i];
    }
    #pragma unroll
    for (int off = 32; off > 0; off >>= 1) {
        a += __shfl_down(a, off);
        b += __shfl_down(b, off);
    }
    __shared__ float sm[32];
    const int wid = threadIdx.x >> 6;      // 16 waves
    if ((threadIdx.x & 63) == 0) { sm[wid] = a; sm[16 + wid] = b; }
    __syncthreads();
    if (threadIdx.x == 0) {
        float num = 0.f, den = 0.f;
        #pragma unroll
        for (int i = 0; i < 16; ++i) { num += sm[i]; den += sm[16 + i]; }
        reg_out[0] = num / fmaxf(den, 1.0f);
    }
}

extern "C" void kernel_launch(void* const* d_in, const int* in_sizes, int n_in,
                              void* d_out, int out_size, void* d_ws, size_t ws_size,
                              hipStream_t stream)
{
    // inputs: verts(analytic), indices(analytic), sdf, deform, weights
    const float* sdf     = (const float*)d_in[2];
    const float* deform  = (const float*)d_in[3];
    const float* weights = (const float*)d_in[4];
    float* out = (float*)d_out;

    float4* vdef4  = (float4*)d_ws;                       // 14.6MB
    float* partial = (float*)((char*)d_ws + (size_t)NVERT * sizeof(float4));

    flexi_vdef<<<(NVERT + 255) / 256, 256, 0, stream>>>(sdf, deform, vdef4);
    flexi_main<<<NBLK, 256, 0, stream>>>(vdef4, weights, out, partial);
    flexi_reduce<<<1, 1024, 0, stream>>>(partial, out + (size_t)NCELLS * 3);
}

// Round 17
// 26.161 us; speedup vs baseline: 1.1971x; 1.1971x over previous
//
#include <hip/hip_runtime.h>
#include <math.h>

#define RES 96
#define NV 97
#define NV2 (NV * NV)                      // 9409
#define NCELLS (RES * RES * RES)           // 884736
#define NBLK 1728                          // 24*24*3 tiles of 4x4x32
#define MAX_DISP (2.0f / 96.0f / 4.0f)
#define NVT 825                            // 5*5*33 tile vertices

typedef float f32x2u __attribute__((ext_vector_type(2), aligned(4)));

__device__ __forceinline__ float grid_coord(int a) {
    // linspace(-0.5,0.5,97)[a] * 2  ==  a/48 - 1
    return fmaf((float)a, 1.0f / 48.0f, -1.0f);
}

__device__ __forceinline__ float fast_tanh(float x) {
    x = fminf(fmaxf(x, -15.f), 15.f);
    const float e = __expf(2.f * x);
    return (e - 1.f) * __builtin_amdgcn_rcpf(e + 1.f);
}

// Full per-cell FlexiCubes dual-vertex computation (corner reads from LDS,
// weights direct global->regs, single-pass edge loop with p[] in regs).
__device__ __forceinline__ void cell_compute(
    const float4* __restrict__ vs4,
    const float* __restrict__ weights,
    float* __restrict__ out_vd,
    const int vbase, const int c,
    float& regc, float& cnt)
{
    const int OFF[8] = {0, 165, 33, 198, 1, 166, 34, 199};  // di*165+dj*33+dk

    float s[8], x[8][3];
    #pragma unroll
    for (int k = 0; k < 8; ++k) {
        const float4 vv = vs4[vbase + OFF[k]];
        x[k][0] = vv.x; x[k][1] = vv.y; x[k][2] = vv.z;
        s[k] = vv.w;
    }

    const float* wrow = weights + (size_t)c * 21;
    float myw[21];                         // beta[0..11], alpha[12..19], gamma[20]
    #pragma unroll
    for (int e = 0; e < 21; ++e) myw[e] = wrow[e];

    const int EA[12] = {0, 1, 4, 0, 2, 3, 6, 2, 2, 3, 7, 6};
    const int EB[12] = {1, 5, 5, 4, 3, 7, 7, 6, 0, 1, 5, 4};

    float p[12][3];
    bool  cross[12];
    float wsum = 0.f, vnum0 = 0.f, vnum1 = 0.f, vnum2 = 0.f;
    int   ncross = 0;
    #pragma unroll
    for (int e = 0; e < 12; ++e) {
        const int a = EA[e], b = EB[e];
        const float sa = s[a], sb = s[b];
        const bool cr = (sa > 0.f) != (sb > 0.f);
        cross[e] = cr;
        const float ta = myw[12 + a] * sb;
        const float tb = myw[12 + b] * sa;
        // den guard keeps p finite (w=0 masks its value, but 0*inf = NaN)
        const float den = cr ? (ta - tb) : 1.0f;
        const float inv = __builtin_amdgcn_rcpf(den);
        const float p0 = (ta * x[a][0] - tb * x[b][0]) * inv;
        const float p1 = (ta * x[a][1] - tb * x[b][1]) * inv;
        const float p2 = (ta * x[a][2] - tb * x[b][2]) * inv;
        p[e][0] = p0; p[e][1] = p1; p[e][2] = p2;
        const float w = cr ? myw[e] : 0.f;
        wsum  += w;
        vnum0 += w * p0;
        vnum1 += w * p1;
        vnum2 += w * p2;
        ncross += cr ? 1 : 0;
    }

    const bool surf = (ncross > 0);
    const float invden = __builtin_amdgcn_rcpf(surf ? wsum : 1.0f);
    float vd0 = vnum0 * invden;
    float vd1 = vnum1 * invden;
    float vd2 = vnum2 * invden;
    if (!surf) { vd0 = 0.f; vd1 = 0.f; vd2 = 0.f; }

    out_vd[(size_t)c * 3 + 0] = vd0;
    out_vd[(size_t)c * 3 + 1] = vd1;
    out_vd[(size_t)c * 3 + 2] = vd2;

    float devsum = 0.f;
    #pragma unroll
    for (int e = 0; e < 12; ++e) {
        const float d0 = p[e][0] - vd0;
        const float d1 = p[e][1] - vd1;
        const float d2 = p[e][2] - vd2;
        const float nrm = __builtin_amdgcn_sqrtf(d0 * d0 + d1 * d1 + d2 * d2 + 1e-12f);
        devsum += cross[e] ? nrm : 0.f;
    }
    const float dev = devsum * __builtin_amdgcn_rcpf(fmaxf((float)ncross, 1.0f));
    regc = surf ? dev * myw[20] : 0.f;
    cnt  = surf ? 1.0f : 0.f;
}

// R13 structure with a 4x4x32 tile: 256 threads, TWO cells per thread
// (k and k+16). Two independent compute chains per thread (ILP fills the
// latency-stall slots) + half the blocks/barriers; staging redundancy
// 1.66 -> 1.61. Hard-won constraints: no nt hints (R12), no same-address
// atomic tails (R6/R7), no forced VGPR bounds (R11), no split passes (R16),
// no p-recompute (R14).
__global__ __launch_bounds__(256) void flexi_fused(
    const float* __restrict__ sdf,
    const float* __restrict__ deform,
    const float* __restrict__ weights,
    float* __restrict__ out_vd,
    float* __restrict__ partial)
{
    __shared__ float4 vs4[NVT];            // (x,y,z,sdf) per tile vertex, 13.2KB
    __shared__ float  sm[8];

    const int t = threadIdx.x;
    // chunked XCD swizzle (bijective: 1728 = 8*216)
    const int bidx = (blockIdx.x & 7) * 216 + (blockIdx.x >> 3);
    const int bi = bidx / 72;              // i-tile (0..23)
    const int rb = bidx - bi * 72;
    const int bj = rb / 3;                 // j-tile (0..23)
    const int bk = rb - bj * 3;            // k-tile (0..2)

    // ---- stage tile vertices: (deformed pos, sdf) as float4 ----
    #pragma unroll
    for (int it = 0; it < 4; ++it) {
        const int u = t + it * 256;
        if (u < NVT) {
            const int a  = u / 165;            // 0..4
            const int r  = u - a * 165;
            const int b  = r / 33;             // 0..4
            const int cc = r - b * 33;         // 0..32
            const int gv = (4 * bi + a) * NV2 + (4 * bj + b) * NV + 32 * bk + cc;
            const float* dp = deform + (size_t)gv * 3;
            const f32x2u d01 = *reinterpret_cast<const f32x2u*>(dp);
            const float  d2  = dp[2];
            float4 vv;
            vv.x = grid_coord(4 * bi + a)   + MAX_DISP * fast_tanh(d01.x);
            vv.y = grid_coord(4 * bj + b)   + MAX_DISP * fast_tanh(d01.y);
            vv.z = grid_coord(32 * bk + cc) + MAX_DISP * fast_tanh(d2);
            vv.w = sdf[gv];
            vs4[u] = vv;
        }
    }
    __syncthreads();

    // ---- two cells per thread: (ti,tj,tk) and (ti,tj,tk+16) ----
    const int ti = t >> 6;
    const int tj = (t >> 4) & 3;
    const int tk = t & 15;
    const int vbase = ti * 165 + tj * 33 + tk;
    const int c = (4 * bi + ti) * 9216 + (4 * bj + tj) * 96 + 32 * bk + tk;

    float rA, cA_, rB, cB_;
    cell_compute(vs4, weights, out_vd, vbase,      c,      rA, cA_);
    cell_compute(vs4, weights, out_vd, vbase + 16, c + 16, rB, cB_);

    float regc = rA + rB;
    float cnt  = cA_ + cB_;

    #pragma unroll
    for (int off = 32; off > 0; off >>= 1) {
        regc += __shfl_down(regc, off);
        cnt  += __shfl_down(cnt, off);
    }
    const int wid = t >> 6;
    if ((t & 63) == 0) { sm[wid] = regc; sm[4 + wid] = cnt; }
    __syncthreads();
    if (t == 0) {
        partial[bidx]        = sm[0] + sm[1] + sm[2] + sm[3];
        partial[NBLK + bidx] = sm[4] + sm[5] + sm[6] + sm[7];
    }
}

__global__ __launch_bounds__(1024) void flexi_reduce(
    const float* __restrict__ partial, float* __restrict__ reg_out)
{
    float a = 0.f, b = 0.f;
    for (int i = threadIdx.x; i < NBLK; i += 1024) {
        a += partial[i];
        b += partial[NBLK + i];
    }
    #pragma unroll
    for (int off = 32; off > 0; off >>= 1) {
        a += __shfl_down(a, off);
        b += __shfl_down(b, off);
    }
    __shared__ float sm[32];
    const int wid = threadIdx.x >> 6;      // 16 waves
    if ((threadIdx.x & 63) == 0) { sm[wid] = a; sm[16 + wid] = b; }
    __syncthreads();
    if (threadIdx.x == 0) {
        float num = 0.f, den = 0.f;
        #pragma unroll
        for (int i = 0; i < 16; ++i) { num += sm[i]; den += sm[16 + i]; }
        reg_out[0] = num / fmaxf(den, 1.0f);
    }
}

extern "C" void kernel_launch(void* const* d_in, const int* in_sizes, int n_in,
                              void* d_out, int out_size, void* d_ws, size_t ws_size,
                              hipStream_t stream)
{
    // inputs: verts(analytic), indices(analytic), sdf, deform, weights
    const float* sdf     = (const float*)d_in[2];
    const float* deform  = (const float*)d_in[3];
    const float* weights = (const float*)d_in[4];
    float* out     = (float*)d_out;
    float* partial = (float*)d_ws;     // 2*NBLK floats, all rewritten each call

    flexi_fused<<<NBLK, 256, 0, stream>>>(sdf, deform, weights, out, partial);
    flexi_reduce<<<1, 1024, 0, stream>>>(partial, out + (size_t)NCELLS * 3);
}